// Round 14
// baseline (370.918 us; speedup 1.0000x reference)
//
#include <hip/hip_runtime.h>
#include <stdint.h>

#define EPS_VAL 2.220446049250313e-16f

typedef unsigned short u16;
typedef __bf16 bf16x8 __attribute__((ext_vector_type(8)));
typedef float f32x4 __attribute__((ext_vector_type(4)));

static __device__ __forceinline__ u16 f2bf(float v) {
    __bf16 b = (__bf16)v;
    return __builtin_bit_cast(u16, b);
}
static __device__ __forceinline__ float bf2f(u16 u) {
    __bf16 b = __builtin_bit_cast(__bf16, u);
    return (float)b;
}
static __device__ __forceinline__ void gll16(const void* g, void* l) {
    __builtin_amdgcn_global_load_lds(
        (const __attribute__((address_space(1))) unsigned int*)g,
        (__attribute__((address_space(3))) unsigned int*)l, 16, 0, 0);
}

#define MT_CAP 40   // tiles of 128 rows per expert (5120-row capacity, >> ~4100 observed)

// ---------------- transpose + convert: in [R][C] f32 -> out [C][R] bf16 ----------------
__global__ void k_transpose_cvt(const float* __restrict__ in, u16* __restrict__ out,
                                int R, int C) {
    __shared__ float t[32][33];
    const float* ip = in + (size_t)blockIdx.z * R * C;
    u16* op = out + (size_t)blockIdx.z * R * C;
    int tx = threadIdx.x & 31, ty = threadIdx.x >> 5;
    int c = blockIdx.x * 32 + tx;
    #pragma unroll
    for (int i = 0; i < 4; ++i) {
        int r = blockIdx.y * 32 + ty + i * 8;
        t[ty + i * 8][tx] = ip[(size_t)r * C + c];
    }
    __syncthreads();
    int r2 = blockIdx.y * 32 + tx;
    #pragma unroll
    for (int i = 0; i < 4; ++i) {
        int c2 = blockIdx.x * 32 + ty + i * 8;
        op[(size_t)c2 * R + r2] = f2bf(t[tx][ty + i * 8]);
    }
}

// ------- gating: 64 rows/block, LDS histogram + ranks, 7 global atomics/block -------
__global__ __launch_bounds__(1024) void k_gate(
    const float* __restrict__ x, const float* __restrict__ wg,
    u16* __restrict__ xb, int* __restrict__ cnt,
    uint2* __restrict__ asg, float4* __restrict__ rec) {
    __shared__ int hist[8];
    __shared__ int basep[8];
    __shared__ int   eA[64], eB[64], rA[64], rB[64];
    __shared__ float gA[64], gB[64];

    const int tid = threadIdx.x;
    if (tid < 8) hist[tid] = 0;
    __syncthreads();

    const int wv = tid >> 6, lane = tid & 63;
    #pragma unroll
    for (int it = 0; it < 4; ++it) {
        int rl  = it * 16 + wv;
        int row = blockIdx.x * 64 + rl;
        const float4* px = (const float4*)(x + (size_t)row * 512) + lane * 2;
        float4 v0 = px[0], v1 = px[1];
        union { u16 h[8]; uint4 u; } o;
        o.h[0]=f2bf(v0.x); o.h[1]=f2bf(v0.y); o.h[2]=f2bf(v0.z); o.h[3]=f2bf(v0.w);
        o.h[4]=f2bf(v1.x); o.h[5]=f2bf(v1.y); o.h[6]=f2bf(v1.z); o.h[7]=f2bf(v1.w);
        ((uint4*)(xb + (size_t)row * 512))[lane] = o.u;

        float xv[8] = {v0.x, v0.y, v0.z, v0.w, v1.x, v1.y, v1.z, v1.w};
        float a0=0,a1=0,a2=0,a3=0,a4=0,a5=0,a6=0,a7=0;
        const float4* wp = (const float4*)wg + (size_t)lane * 16;
        #pragma unroll
        for (int j = 0; j < 8; ++j) {
            float4 wa = wp[j * 2], wb = wp[j * 2 + 1];
            float v = xv[j];
            a0 += v*wa.x; a1 += v*wa.y; a2 += v*wa.z; a3 += v*wa.w;
            a4 += v*wb.x; a5 += v*wb.y; a6 += v*wb.z; a7 += v*wb.w;
        }
        #pragma unroll
        for (int off = 32; off; off >>= 1) {
            a0 += __shfl_xor(a0, off); a1 += __shfl_xor(a1, off);
            a2 += __shfl_xor(a2, off); a3 += __shfl_xor(a3, off);
            a4 += __shfl_xor(a4, off); a5 += __shfl_xor(a5, off);
            a6 += __shfl_xor(a6, off); a7 += __shfl_xor(a7, off);
        }
        if (lane == 0) {
            float v[8] = {a0,a1,a2,a3,a4,a5,a6,a7};
            int i0 = 0;
            #pragma unroll
            for (int e = 1; e < 8; ++e) if (v[e] > v[i0]) i0 = e;
            int i1 = (i0 == 0) ? 1 : 0;
            #pragma unroll
            for (int e = 0; e < 8; ++e) if (e != i0 && v[e] > v[i1]) i1 = e;
            float ex = expf(v[i1] - v[i0]);
            float g0 = 1.f / (1.f + ex), g1 = ex / (1.f + ex);
            rec[row] = make_float4(__int_as_float(i0), __int_as_float(i1), g0, g1);
            int r0 = (i0 != 7) ? atomicAdd(&hist[i0], 1) : -1;
            int r1 = (i1 != 7) ? atomicAdd(&hist[i1], 1) : -1;
            eA[rl] = i0; eB[rl] = i1; rA[rl] = r0; rB[rl] = r1;
            gA[rl] = g0; gB[rl] = g1;
        }
    }
    __syncthreads();
    if (tid < 7) basep[tid] = atomicAdd(&cnt[tid], hist[tid]);
    __syncthreads();
    if (tid < 64) {
        int row = blockIdx.x * 64 + tid;
        int i0 = eA[tid], i1 = eB[tid];
        if (i0 != 7)
            asg[i0 * 16384 + basep[i0] + rA[tid]] =
                make_uint2((unsigned)(row << 1), __float_as_uint(gA[tid]));
        if (i1 != 7)
            asg[i1 * 16384 + basep[i1] + rB[tid]] =
                make_uint2((unsigned)((row << 1) | 1), __float_as_uint(gB[tid]));
    }
}

// ---------------- prefix offsets over expert counts ----------------
__global__ void k_prefix(const int* __restrict__ cnt, int* __restrict__ off) {
    if (threadIdx.x == 0) {
        int s = 0;
        for (int e = 0; e < 7; ++e) { off[e] = s; s += cnt[e]; }
        off[7] = s;
    }
}

// Triple-buffered counted-vmcnt K-loop shared shape:
// smem: buf b at b*20480 (A 10240 + B 10240), b in {0,1,2}.
// Per K-step per thread gll count L: waves 0-1 -> 6, waves 2-3 -> 4.
// One s_barrier per K-step preceded by s_waitcnt vmcnt(L) (tail: vmcnt(0)).

// ------- E1: H[off[e]+i][hcol] = relu(Xg @ W1 + b1), 128x128 tile, BK=32 -------
__global__ __launch_bounds__(256) void k_e1(
    const u16* __restrict__ xb, const u16* __restrict__ w1t,
    const float* __restrict__ b1, const int* __restrict__ cnt,
    const int* __restrict__ off, const uint2* __restrict__ asg,
    u16* __restrict__ Hb, int h0, int S, int NT)
{
    __shared__ __attribute__((aligned(16))) char smem[61440];

    const int bid = blockIdx.x;
    const int t0  = (bid & 7) * (35 * NT) + (bid >> 3);
    const int e   = t0 / (MT_CAP * NT);
    const int rem = t0 - e * (MT_CAP * NT);
    const int mt  = rem / NT;
    const int nt  = rem - mt * NT;

    const int ce  = cnt[e];
    const int mtb = mt * 128;
    if (mtb >= ce) return;
    const int ntb = nt * 128;

    const int tid = threadIdx.x, wv = tid >> 6, lane = tid & 63;
    const int l16 = lane & 15, q = lane >> 4;
    const int wr = wv >> 1, wc = wv & 1;
    const u16* w1p = w1t + (size_t)e * 2048 * 512;

    const int nj = (wv < 2) ? 3 : 2;
    const u16* aS[3]; const u16* bS[3]; int js[3];
    #pragma unroll
    for (int jj = 0; jj < 3; ++jj) {
        int j = wv + jj * 4; js[jj] = j;
        if (j < 10) {
            int g = j * 64 + lane, row = g / 5, sl = g % 5;
            if (sl == 4) sl = 0;                       // pad slot: dummy source
            int idx = mtb + row;
            int rs = 0;
            if (idx < ce) rs = (int)asg[e * 16384 + idx].x >> 1;
            aS[jj] = xb + (size_t)rs * 512 + sl * 8;
            bS[jj] = w1p + (size_t)(h0 + ntb + row) * 512 + sl * 8;
        } else { aS[jj] = xb; bS[jj] = w1p; }
    }

    auto ISSUE = [&](int b) {
        char* An = smem + (b % 3) * 20480;
        char* Bn = An + 10240;
        int ko = b * 32;
        #pragma unroll
        for (int jj = 0; jj < 3; ++jj) if (jj < nj) {
            gll16(aS[jj] + ko, An + js[jj] * 1024);
            gll16(bS[jj] + ko, Bn + js[jj] * 1024);
        }
    };

    // prologue: batches 0 and 1 in flight; wait batch 0 only
    ISSUE(0);
    ISSUE(1);
    if (wv < 2) asm volatile("s_waitcnt vmcnt(6) lgkmcnt(0)" ::: "memory");
    else        asm volatile("s_waitcnt vmcnt(4) lgkmcnt(0)" ::: "memory");
    __builtin_amdgcn_s_barrier();
    __builtin_amdgcn_sched_barrier(0);

    f32x4 acc[4][4];
    #pragma unroll
    for (int mti = 0; mti < 4; ++mti)
        #pragma unroll
        for (int nti = 0; nti < 4; ++nti) acc[mti][nti] = (f32x4){0.f, 0.f, 0.f, 0.f};

    const int KT = 16;
    for (int t = 0; t < KT; ++t) {
        if (t + 2 < KT) ISSUE(t + 2);

        const char* Ab = smem + (t % 3) * 20480;
        const char* Bb = Ab + 10240;
        bf16x8 af[4], bf[4];
        #pragma unroll
        for (int mti = 0; mti < 4; ++mti)
            af[mti] = *(const bf16x8*)(Ab + (wr * 64 + mti * 16 + l16) * 80 + q * 16);
        #pragma unroll
        for (int nti = 0; nti < 4; ++nti)
            bf[nti] = *(const bf16x8*)(Bb + (wc * 64 + nti * 16 + l16) * 80 + q * 16);
        #pragma unroll
        for (int mti = 0; mti < 4; ++mti)
            #pragma unroll
            for (int nti = 0; nti < 4; ++nti)
                acc[mti][nti] = __builtin_amdgcn_mfma_f32_16x16x32_bf16(
                    af[mti], bf[nti], acc[mti][nti], 0, 0, 0);

        if (t < KT - 1) {
            if (t < KT - 2) {
                if (wv < 2) asm volatile("s_waitcnt vmcnt(6) lgkmcnt(0)" ::: "memory");
                else        asm volatile("s_waitcnt vmcnt(4) lgkmcnt(0)" ::: "memory");
            } else {
                asm volatile("s_waitcnt vmcnt(0) lgkmcnt(0)" ::: "memory");
            }
            __builtin_amdgcn_s_barrier();
            __builtin_amdgcn_sched_barrier(0);
        }
    }

    const size_t hbase = (size_t)off[e];
    #pragma unroll
    for (int nti = 0; nti < 4; ++nti) {
        int hcol = ntb + wc * 64 + nti * 16 + l16;
        float bias = b1[e * 2048 + h0 + hcol];
        #pragma unroll
        for (int mti = 0; mti < 4; ++mti) {
            #pragma unroll
            for (int r = 0; r < 4; ++r) {
                int i = mtb + wr * 64 + mti * 16 + q * 4 + r;
                if (i < ce) {
                    float v = acc[mti][nti][r] + bias;
                    v = v > 0.f ? v : 0.f;
                    Hb[(hbase + i) * S + hcol] = f2bf(v);
                }
            }
        }
    }
}

// ------- E2: ybuf[slot][grow] (+)= g*(H @ W2 + b2), 128x128 tile, K=S -------
__global__ __launch_bounds__(256) void k_e2(
    const u16* __restrict__ Hb, const u16* __restrict__ w2t,
    const float* __restrict__ b2, const int* __restrict__ cnt,
    const int* __restrict__ off, const uint2* __restrict__ asg,
    u16* __restrict__ ybuf, int h0, int S, int firstPass, int lastPass)
{
    __shared__ __attribute__((aligned(16))) char smem[61440];

    const int bid = blockIdx.x;
    const int t0  = (bid & 7) * 140 + (bid >> 3);      // 7*40*4/8 = 140 per XCD
    const int e   = t0 / (MT_CAP * 4);
    const int rem = t0 - e * (MT_CAP * 4);
    const int mt  = rem >> 2;
    const int dt  = rem & 3;

    const int ce  = cnt[e];
    const int mtb = mt * 128;
    if (mtb >= ce) return;
    const int dtb = dt * 128;

    const int tid = threadIdx.x, wv = tid >> 6, lane = tid & 63;
    const int l16 = lane & 15, q = lane >> 4;
    const int wr = wv >> 1, wc = wv & 1;
    const u16* w2p = w2t + (size_t)e * 512 * 2048;
    const size_t hbase = (size_t)off[e];

    const int nj = (wv < 2) ? 3 : 2;
    const u16* aS[3]; const u16* bS[3]; int js[3];
    #pragma unroll
    for (int jj = 0; jj < 3; ++jj) {
        int j = wv + jj * 4; js[jj] = j;
        if (j < 10) {
            int g = j * 64 + lane, row = g / 5, sl = g % 5;
            if (sl == 4) sl = 0;
            aS[jj] = Hb + (hbase + mtb + row) * S + sl * 8;
            bS[jj] = w2p + (size_t)(dtb + row) * 2048 + h0 + sl * 8;
        } else { aS[jj] = Hb; bS[jj] = w2p; }
    }

    auto ISSUE = [&](int b) {
        char* An = smem + (b % 3) * 20480;
        char* Bn = An + 10240;
        int ko = b * 32;
        #pragma unroll
        for (int jj = 0; jj < 3; ++jj) if (jj < nj) {
            gll16(aS[jj] + ko, An + js[jj] * 1024);
            gll16(bS[jj] + ko, Bn + js[jj] * 1024);
        }
    };

    ISSUE(0);
    ISSUE(1);
    if (wv < 2) asm volatile("s_waitcnt vmcnt(6) lgkmcnt(0)" ::: "memory");
    else        asm volatile("s_waitcnt vmcnt(4) lgkmcnt(0)" ::: "memory");
    __builtin_amdgcn_s_barrier();
    __builtin_amdgcn_sched_barrier(0);

    f32x4 acc[4][4];
    #pragma unroll
    for (int mti = 0; mti < 4; ++mti)
        #pragma unroll
        for (int nti = 0; nti < 4; ++nti) acc[mti][nti] = (f32x4){0.f, 0.f, 0.f, 0.f};

    const int KT = S >> 5;
    for (int t = 0; t < KT; ++t) {
        if (t + 2 < KT) ISSUE(t + 2);

        const char* Ab = smem + (t % 3) * 20480;
        const char* Bb = Ab + 10240;
        bf16x8 af[4], bf[4];
        #pragma unroll
        for (int mti = 0; mti < 4; ++mti)
            af[mti] = *(const bf16x8*)(Ab + (wr * 64 + mti * 16 + l16) * 80 + q * 16);
        #pragma unroll
        for (int nti = 0; nti < 4; ++nti)
            bf[nti] = *(const bf16x8*)(Bb + (wc * 64 + nti * 16 + l16) * 80 + q * 16);
        #pragma unroll
        for (int mti = 0; mti < 4; ++mti)
            #pragma unroll
            for (int nti = 0; nti < 4; ++nti)
                acc[mti][nti] = __builtin_amdgcn_mfma_f32_16x16x32_bf16(
                    af[mti], bf[nti], acc[mti][nti], 0, 0, 0);

        if (t < KT - 1) {
            if (t < KT - 2) {
                if (wv < 2) asm volatile("s_waitcnt vmcnt(6) lgkmcnt(0)" ::: "memory");
                else        asm volatile("s_waitcnt vmcnt(4) lgkmcnt(0)" ::: "memory");
            } else {
                asm volatile("s_waitcnt vmcnt(0) lgkmcnt(0)" ::: "memory");
            }
            __builtin_amdgcn_s_barrier();
            __builtin_amdgcn_sched_barrier(0);
        }
    }

    #pragma unroll
    for (int nti = 0; nti < 4; ++nti) {
        int d = dtb + wc * 64 + nti * 16 + l16;
        float b2v = b2[e * 512 + d];
        #pragma unroll
        for (int mti = 0; mti < 4; ++mti) {
            #pragma unroll
            for (int r = 0; r < 4; ++r) {
                int lrow = wr * 64 + mti * 16 + q * 4 + r;
                int i = mtb + lrow;
                if (i < ce) {
                    uint2 a = asg[e * 16384 + i];
                    int rs = (int)a.x;
                    float g = __builtin_bit_cast(float, a.y);
                    float v = acc[mti][nti][r];
                    size_t yo = ((size_t)(rs & 1) * 16384 + (rs >> 1)) * 512 + d;
                    if (!firstPass) v += bf2f(ybuf[yo]);
                    if (lastPass)   v = g * (v + b2v);
                    ybuf[yo] = f2bf(v);
                }
            }
        }
    }
}

// ---------------- final combine + EPS replacement ----------------
__global__ void k_final(const float* __restrict__ x, const float4* __restrict__ rec,
                        const u16* __restrict__ ybuf, float* __restrict__ out) {
    int i = blockIdx.x * 256 + threadIdx.x;
    int row = i >> 7;
    float4 r = rec[row];
    int e0 = __float_as_int(r.x), e1 = __float_as_int(r.y);
    float g7 = (e0 == 7) ? r.z : ((e1 == 7) ? r.w : 0.f);
    float4 xv = ((const float4*)x)[i];
    float o0 = g7 * xv.x, o1 = g7 * xv.y, o2 = g7 * xv.z, o3 = g7 * xv.w;
    size_t off = (size_t)i * 4;
    if (e0 != 7) {
        uint2 y = *(const uint2*)(ybuf + off);
        o0 += bf2f((u16)(y.x & 0xffff)); o1 += bf2f((u16)(y.x >> 16));
        o2 += bf2f((u16)(y.y & 0xffff)); o3 += bf2f((u16)(y.y >> 16));
    }
    if (e1 != 7) {
        uint2 y = *(const uint2*)(ybuf + 8388608 + off);
        o0 += bf2f((u16)(y.x & 0xffff)); o1 += bf2f((u16)(y.x >> 16));
        o2 += bf2f((u16)(y.y & 0xffff)); o3 += bf2f((u16)(y.y >> 16));
    }
    float4 res;
    res.x = (o0 == 0.f) ? EPS_VAL : o0;
    res.y = (o1 == 0.f) ? EPS_VAL : o1;
    res.z = (o2 == 0.f) ? EPS_VAL : o2;
    res.w = (o3 == 0.f) ? EPS_VAL : o3;
    ((float4*)out)[i] = res;
}

extern "C" void kernel_launch(void* const* d_in, const int* in_sizes, int n_in,
                              void* d_out, int out_size, void* d_ws, size_t ws_size,
                              hipStream_t stream) {
    const float* x  = (const float*)d_in[0];
    const float* wg = (const float*)d_in[1];
    const float* W1 = (const float*)d_in[2];
    const float* b1 = (const float*)d_in[3];
    const float* W2 = (const float*)d_in[4];
    const float* b2 = (const float*)d_in[5];
    (void)in_sizes; (void)n_in; (void)out_size;

    char* ws = (char*)d_ws;
    int*    cnt  = (int*)ws;                  // 7 ints @0
    int*    off  = (int*)(ws + 64);           // 8 ints @64
    float4* rec  = (float4*)(ws + 256);       // 256 KB
    uint2*  asg  = (uint2*)(ws + 262400);     // 896 KB
    u16*    xb   = (u16*)(ws + 1179904);      // 16 MB
    u16*    w1t  = (u16*)(ws + 17957120);     // 14.68 MB
    u16*    w2t  = (u16*)(ws + 32637184);     // 14.68 MB
    u16*    ybuf = (u16*)(ws + 47317248);     // 32 MB -> ends 80871680
    u16*    Hb   = (u16*)(ws + 80871680);     // 32896 rows x S bf16

    // pick largest stripe S whose H buffer fits the workspace
    int S = 128;
    const int cands[4] = {2048, 1024, 512, 256};
    for (int c = 0; c < 4; ++c) {
        if (ws_size >= 80871680ull + (size_t)32896 * cands[c] * 2) { S = cands[c]; break; }
    }
    const int passes = 2048 / S;

    hipMemsetAsync(ws, 0, 256, stream);
    k_transpose_cvt<<<dim3(64, 16, 7), 256, 0, stream>>>(W1, w1t, 512, 2048);
    k_transpose_cvt<<<dim3(16, 64, 7), 256, 0, stream>>>(W2, w2t, 2048, 512);
    k_gate<<<256, 1024, 0, stream>>>(x, wg, xb, cnt, asg, rec);
    k_prefix<<<1, 64, 0, stream>>>(cnt, off);
    for (int p = 0; p < passes; ++p) {
        int h0 = p * S;
        int NT = S / 128;
        k_e1<<<7 * MT_CAP * NT, 256, 0, stream>>>(xb, w1t, b1, cnt, off, asg, Hb, h0, S, NT);
        k_e2<<<7 * MT_CAP * 4, 256, 0, stream>>>(Hb, w2t, b2, cnt, off, asg, ybuf,
                                                 h0, S, p == 0 ? 1 : 0,
                                                 p == passes - 1 ? 1 : 0);
    }
    k_final<<<8192, 256, 0, stream>>>(x, rec, ybuf, (float*)d_out);
}

// Round 15
// 311.732 us; speedup vs baseline: 1.1899x; 1.1899x over previous
//
#include <hip/hip_runtime.h>
#include <stdint.h>

#define EPS_VAL 2.220446049250313e-16f

typedef unsigned short u16;
typedef __bf16 bf16x8 __attribute__((ext_vector_type(8)));
typedef float f32x4 __attribute__((ext_vector_type(4)));

static __device__ __forceinline__ u16 f2bf(float v) {
    __bf16 b = (__bf16)v;
    return __builtin_bit_cast(u16, b);
}
static __device__ __forceinline__ float bf2f(u16 u) {
    __bf16 b = __builtin_bit_cast(__bf16, u);
    return (float)b;
}
static __device__ __forceinline__ void gll16(const void* g, void* l) {
    __builtin_amdgcn_global_load_lds(
        (const __attribute__((address_space(1))) unsigned int*)g,
        (__attribute__((address_space(3))) unsigned int*)l, 16, 0, 0);
}

#define MT_CAP 40   // tiles of 128 rows per expert (5120-row capacity, >> ~4100 observed)

// ---------------- transpose + convert: in [R][C] f32 -> out [C][R] bf16 ----------------
__global__ void k_transpose_cvt(const float* __restrict__ in, u16* __restrict__ out,
                                int R, int C) {
    __shared__ float t[32][33];
    const float* ip = in + (size_t)blockIdx.z * R * C;
    u16* op = out + (size_t)blockIdx.z * R * C;
    int tx = threadIdx.x & 31, ty = threadIdx.x >> 5;
    int c = blockIdx.x * 32 + tx;
    #pragma unroll
    for (int i = 0; i < 4; ++i) {
        int r = blockIdx.y * 32 + ty + i * 8;
        t[ty + i * 8][tx] = ip[(size_t)r * C + c];
    }
    __syncthreads();
    int r2 = blockIdx.y * 32 + tx;
    #pragma unroll
    for (int i = 0; i < 4; ++i) {
        int c2 = blockIdx.x * 32 + ty + i * 8;
        op[(size_t)c2 * R + r2] = f2bf(t[tx][ty + i * 8]);
    }
}

// ------- gating: 64 rows/block, LDS histogram + ranks, 7 global atomics/block -------
__global__ __launch_bounds__(1024) void k_gate(
    const float* __restrict__ x, const float* __restrict__ wg,
    u16* __restrict__ xb, int* __restrict__ cnt,
    uint2* __restrict__ asg, float4* __restrict__ rec) {
    __shared__ int hist[8];
    __shared__ int basep[8];
    __shared__ int   eA[64], eB[64], rA[64], rB[64];
    __shared__ float gA[64], gB[64];

    const int tid = threadIdx.x;
    if (tid < 8) hist[tid] = 0;
    __syncthreads();

    const int wv = tid >> 6, lane = tid & 63;
    #pragma unroll
    for (int it = 0; it < 4; ++it) {
        int rl  = it * 16 + wv;
        int row = blockIdx.x * 64 + rl;
        const float4* px = (const float4*)(x + (size_t)row * 512) + lane * 2;
        float4 v0 = px[0], v1 = px[1];
        union { u16 h[8]; uint4 u; } o;
        o.h[0]=f2bf(v0.x); o.h[1]=f2bf(v0.y); o.h[2]=f2bf(v0.z); o.h[3]=f2bf(v0.w);
        o.h[4]=f2bf(v1.x); o.h[5]=f2bf(v1.y); o.h[6]=f2bf(v1.z); o.h[7]=f2bf(v1.w);
        ((uint4*)(xb + (size_t)row * 512))[lane] = o.u;

        float xv[8] = {v0.x, v0.y, v0.z, v0.w, v1.x, v1.y, v1.z, v1.w};
        float a0=0,a1=0,a2=0,a3=0,a4=0,a5=0,a6=0,a7=0;
        const float4* wp = (const float4*)wg + (size_t)lane * 16;
        #pragma unroll
        for (int j = 0; j < 8; ++j) {
            float4 wa = wp[j * 2], wb = wp[j * 2 + 1];
            float v = xv[j];
            a0 += v*wa.x; a1 += v*wa.y; a2 += v*wa.z; a3 += v*wa.w;
            a4 += v*wb.x; a5 += v*wb.y; a6 += v*wb.z; a7 += v*wb.w;
        }
        #pragma unroll
        for (int off = 32; off; off >>= 1) {
            a0 += __shfl_xor(a0, off); a1 += __shfl_xor(a1, off);
            a2 += __shfl_xor(a2, off); a3 += __shfl_xor(a3, off);
            a4 += __shfl_xor(a4, off); a5 += __shfl_xor(a5, off);
            a6 += __shfl_xor(a6, off); a7 += __shfl_xor(a7, off);
        }
        if (lane == 0) {
            float v[8] = {a0,a1,a2,a3,a4,a5,a6,a7};
            int i0 = 0;
            #pragma unroll
            for (int e = 1; e < 8; ++e) if (v[e] > v[i0]) i0 = e;
            int i1 = (i0 == 0) ? 1 : 0;
            #pragma unroll
            for (int e = 0; e < 8; ++e) if (e != i0 && v[e] > v[i1]) i1 = e;
            float ex = expf(v[i1] - v[i0]);
            float g0 = 1.f / (1.f + ex), g1 = ex / (1.f + ex);
            rec[row] = make_float4(__int_as_float(i0), __int_as_float(i1), g0, g1);
            int r0 = (i0 != 7) ? atomicAdd(&hist[i0], 1) : -1;
            int r1 = (i1 != 7) ? atomicAdd(&hist[i1], 1) : -1;
            eA[rl] = i0; eB[rl] = i1; rA[rl] = r0; rB[rl] = r1;
            gA[rl] = g0; gB[rl] = g1;
        }
    }
    __syncthreads();
    if (tid < 7) basep[tid] = atomicAdd(&cnt[tid], hist[tid]);
    __syncthreads();
    if (tid < 64) {
        int row = blockIdx.x * 64 + tid;
        int i0 = eA[tid], i1 = eB[tid];
        if (i0 != 7)
            asg[i0 * 16384 + basep[i0] + rA[tid]] =
                make_uint2((unsigned)(row << 1), __float_as_uint(gA[tid]));
        if (i1 != 7)
            asg[i1 * 16384 + basep[i1] + rB[tid]] =
                make_uint2((unsigned)((row << 1) | 1), __float_as_uint(gB[tid]));
    }
}

// ---------------- prefix offsets over expert counts ----------------
__global__ void k_prefix(const int* __restrict__ cnt, int* __restrict__ off) {
    if (threadIdx.x == 0) {
        int s = 0;
        for (int e = 0; e < 7; ++e) { off[e] = s; s += cnt[e]; }
        off[7] = s;
    }
}

// Triple-buffered counted-vmcnt K-loop, swizzled unpadded tiles:
// buffer b at (b%3)*16384: A tile [128 r][4 slots*16B] then B tile same (8 KB each).
// 16B-slot s of row r stored at s ^ ((r>>1)&3)  -> 2-way bank access (free).
// Staging: 4 gll16/thread/step (2 A + 2 B), pre-swizzled source, linear dest.
// One s_barrier per K-step preceded by s_waitcnt vmcnt(4) (steady) / vmcnt(0) (tail).

// ------- E1: H[off[e]+i][hcol] = relu(Xg @ W1 + b1), 128x128 tile, BK=32 -------
__global__ __launch_bounds__(256) void k_e1(
    const u16* __restrict__ xb, const u16* __restrict__ w1t,
    const float* __restrict__ b1, const int* __restrict__ cnt,
    const int* __restrict__ off, const uint2* __restrict__ asg,
    u16* __restrict__ Hb, int h0, int S, int NT)
{
    __shared__ __attribute__((aligned(16))) char smem[49152];

    const int bid = blockIdx.x;
    const int t0  = (bid & 7) * (35 * NT) + (bid >> 3);
    const int e   = t0 / (MT_CAP * NT);
    const int rem = t0 - e * (MT_CAP * NT);
    const int mt  = rem / NT;
    const int nt  = rem - mt * NT;

    const int ce  = cnt[e];
    const int mtb = mt * 128;
    if (mtb >= ce) return;
    const int ntb = nt * 128;

    const int tid = threadIdx.x, wv = tid >> 6, lane = tid & 63;
    const int l16 = lane & 15, q = lane >> 4;
    const int wr = wv >> 1, wc = wv & 1;
    const u16* w1p = w1t + (size_t)e * 2048 * 512;

    // staging rows: chunk1 = tid>>2 (0..63), chunk2 = +64; logical slot s_log
    const int rowS  = tid >> 2;
    const int s_log = (lane & 3) ^ ((lane >> 3) & 3);   // = (tid&3) ^ ((rowS>>1)&3)
    int rsA0 = 0, rsA1 = 0;
    { int i0 = mtb + rowS;      if (i0 < ce) rsA0 = (int)asg[e * 16384 + i0].x >> 1; }
    { int i1 = mtb + rowS + 64; if (i1 < ce) rsA1 = (int)asg[e * 16384 + i1].x >> 1; }
    const u16* aS0 = xb + (size_t)rsA0 * 512 + s_log * 8;
    const u16* aS1 = xb + (size_t)rsA1 * 512 + s_log * 8;
    const u16* bS0 = w1p + (size_t)(h0 + ntb + rowS) * 512 + s_log * 8;
    const u16* bS1 = w1p + (size_t)(h0 + ntb + rowS + 64) * 512 + s_log * 8;
    // dest wave-uniform bases (lane*16 added by HW)
    const int dA0 = wv * 1024, dA1 = 4096 + wv * 1024;

    auto ISSUE = [&](int b) {
        char* bufA = smem + (b % 3) * 16384;
        char* bufB = bufA + 8192;
        int ko = b * 32;
        gll16(aS0 + ko, bufA + dA0);
        gll16(aS1 + ko, bufA + dA1);
        gll16(bS0 + ko, bufB + dA0);
        gll16(bS1 + ko, bufB + dA1);
    };

    ISSUE(0);
    ISSUE(1);
    asm volatile("s_waitcnt vmcnt(4) lgkmcnt(0)" ::: "memory");
    __builtin_amdgcn_s_barrier();
    __builtin_amdgcn_sched_barrier(0);

    f32x4 acc[4][4];
    #pragma unroll
    for (int mti = 0; mti < 4; ++mti)
        #pragma unroll
        for (int nti = 0; nti < 4; ++nti) acc[mti][nti] = (f32x4){0.f, 0.f, 0.f, 0.f};

    const int kq = (l16 >> 1) & 3;   // fragment-read swizzle key (row bits 1-2)
    const int KT = 16;
    for (int t = 0; t < KT; ++t) {
        if (t + 2 < KT) ISSUE(t + 2);

        const char* Ab = smem + (t % 3) * 16384;
        const char* Bb = Ab + 8192;
        bf16x8 af[4], bf[4];
        #pragma unroll
        for (int mti = 0; mti < 4; ++mti)
            af[mti] = *(const bf16x8*)(Ab + (wr * 64 + mti * 16 + l16) * 64 +
                                       ((q ^ kq) * 16));
        #pragma unroll
        for (int nti = 0; nti < 4; ++nti)
            bf[nti] = *(const bf16x8*)(Bb + (wc * 64 + nti * 16 + l16) * 64 +
                                       ((q ^ kq) * 16));
        #pragma unroll
        for (int mti = 0; mti < 4; ++mti)
            #pragma unroll
            for (int nti = 0; nti < 4; ++nti)
                acc[mti][nti] = __builtin_amdgcn_mfma_f32_16x16x32_bf16(
                    af[mti], bf[nti], acc[mti][nti], 0, 0, 0);

        if (t < KT - 1) {
            if (t < KT - 2)
                asm volatile("s_waitcnt vmcnt(4) lgkmcnt(0)" ::: "memory");
            else
                asm volatile("s_waitcnt vmcnt(0) lgkmcnt(0)" ::: "memory");
            __builtin_amdgcn_s_barrier();
            __builtin_amdgcn_sched_barrier(0);
        }
    }

    const size_t hbase = (size_t)off[e];
    #pragma unroll
    for (int nti = 0; nti < 4; ++nti) {
        int hcol = ntb + wc * 64 + nti * 16 + l16;
        float bias = b1[e * 2048 + h0 + hcol];
        #pragma unroll
        for (int mti = 0; mti < 4; ++mti) {
            #pragma unroll
            for (int r = 0; r < 4; ++r) {
                int i = mtb + wr * 64 + mti * 16 + q * 4 + r;
                if (i < ce) {
                    float v = acc[mti][nti][r] + bias;
                    v = v > 0.f ? v : 0.f;
                    Hb[(hbase + i) * S + hcol] = f2bf(v);
                }
            }
        }
    }
}

// ------- E2: ybuf[slot][grow] (+)= g*(H @ W2 + b2), 128x128 tile, K=S -------
__global__ __launch_bounds__(256) void k_e2(
    const u16* __restrict__ Hb, const u16* __restrict__ w2t,
    const float* __restrict__ b2, const int* __restrict__ cnt,
    const int* __restrict__ off, const uint2* __restrict__ asg,
    u16* __restrict__ ybuf, int h0, int S, int firstPass, int lastPass)
{
    __shared__ __attribute__((aligned(16))) char smem[49152];

    const int bid = blockIdx.x;
    const int t0  = (bid & 7) * 140 + (bid >> 3);      // 7*40*4/8 = 140 per XCD
    const int e   = t0 / (MT_CAP * 4);
    const int rem = t0 - e * (MT_CAP * 4);
    const int mt  = rem >> 2;
    const int dt  = rem & 3;

    const int ce  = cnt[e];
    const int mtb = mt * 128;
    if (mtb >= ce) return;
    const int dtb = dt * 128;

    const int tid = threadIdx.x, wv = tid >> 6, lane = tid & 63;
    const int l16 = lane & 15, q = lane >> 4;
    const int wr = wv >> 1, wc = wv & 1;
    const u16* w2p = w2t + (size_t)e * 512 * 2048;
    const size_t hbase = (size_t)off[e];

    const int rowS  = tid >> 2;
    const int s_log = (lane & 3) ^ ((lane >> 3) & 3);
    const u16* aS0 = Hb + (hbase + mtb + rowS) * S + h0 + s_log * 8;
    const u16* aS1 = Hb + (hbase + mtb + rowS + 64) * S + h0 + s_log * 8;
    const u16* bS0 = w2p + (size_t)(dtb + rowS) * 2048 + h0 + s_log * 8;
    const u16* bS1 = w2p + (size_t)(dtb + rowS + 64) * 2048 + h0 + s_log * 8;
    const int dA0 = wv * 1024, dA1 = 4096 + wv * 1024;

    auto ISSUE = [&](int b) {
        char* bufA = smem + (b % 3) * 16384;
        char* bufB = bufA + 8192;
        int ko = b * 32;
        gll16(aS0 + ko, bufA + dA0);
        gll16(aS1 + ko, bufA + dA1);
        gll16(bS0 + ko, bufB + dA0);
        gll16(bS1 + ko, bufB + dA1);
    };

    ISSUE(0);
    ISSUE(1);
    asm volatile("s_waitcnt vmcnt(4) lgkmcnt(0)" ::: "memory");
    __builtin_amdgcn_s_barrier();
    __builtin_amdgcn_sched_barrier(0);

    f32x4 acc[4][4];
    #pragma unroll
    for (int mti = 0; mti < 4; ++mti)
        #pragma unroll
        for (int nti = 0; nti < 4; ++nti) acc[mti][nti] = (f32x4){0.f, 0.f, 0.f, 0.f};

    const int kq = (l16 >> 1) & 3;
    const int KT = S >> 5;
    for (int t = 0; t < KT; ++t) {
        if (t + 2 < KT) ISSUE(t + 2);

        const char* Ab = smem + (t % 3) * 16384;
        const char* Bb = Ab + 8192;
        bf16x8 af[4], bf[4];
        #pragma unroll
        for (int mti = 0; mti < 4; ++mti)
            af[mti] = *(const bf16x8*)(Ab + (wr * 64 + mti * 16 + l16) * 64 +
                                       ((q ^ kq) * 16));
        #pragma unroll
        for (int nti = 0; nti < 4; ++nti)
            bf[nti] = *(const bf16x8*)(Bb + (wc * 64 + nti * 16 + l16) * 64 +
                                       ((q ^ kq) * 16));
        #pragma unroll
        for (int mti = 0; mti < 4; ++mti)
            #pragma unroll
            for (int nti = 0; nti < 4; ++nti)
                acc[mti][nti] = __builtin_amdgcn_mfma_f32_16x16x32_bf16(
                    af[mti], bf[nti], acc[mti][nti], 0, 0, 0);

        if (t < KT - 1) {
            if (t < KT - 2)
                asm volatile("s_waitcnt vmcnt(4) lgkmcnt(0)" ::: "memory");
            else
                asm volatile("s_waitcnt vmcnt(0) lgkmcnt(0)" ::: "memory");
            __builtin_amdgcn_s_barrier();
            __builtin_amdgcn_sched_barrier(0);
        }
    }

    #pragma unroll
    for (int nti = 0; nti < 4; ++nti) {
        int d = dtb + wc * 64 + nti * 16 + l16;
        float b2v = b2[e * 512 + d];
        #pragma unroll
        for (int mti = 0; mti < 4; ++mti) {
            #pragma unroll
            for (int r = 0; r < 4; ++r) {
                int lrow = wr * 64 + mti * 16 + q * 4 + r;
                int i = mtb + lrow;
                if (i < ce) {
                    uint2 a = asg[e * 16384 + i];
                    int rs = (int)a.x;
                    float g = __builtin_bit_cast(float, a.y);
                    float v = acc[mti][nti][r];
                    size_t yo = ((size_t)(rs & 1) * 16384 + (rs >> 1)) * 512 + d;
                    if (!firstPass) v += bf2f(ybuf[yo]);
                    if (lastPass)   v = g * (v + b2v);
                    ybuf[yo] = f2bf(v);
                }
            }
        }
    }
}

// ---------------- final combine + EPS replacement ----------------
__global__ void k_final(const float* __restrict__ x, const float4* __restrict__ rec,
                        const u16* __restrict__ ybuf, float* __restrict__ out) {
    int i = blockIdx.x * 256 + threadIdx.x;
    int row = i >> 7;
    float4 r = rec[row];
    int e0 = __float_as_int(r.x), e1 = __float_as_int(r.y);
    float g7 = (e0 == 7) ? r.z : ((e1 == 7) ? r.w : 0.f);
    float4 xv = ((const float4*)x)[i];
    float o0 = g7 * xv.x, o1 = g7 * xv.y, o2 = g7 * xv.z, o3 = g7 * xv.w;
    size_t off = (size_t)i * 4;
    if (e0 != 7) {
        uint2 y = *(const uint2*)(ybuf + off);
        o0 += bf2f((u16)(y.x & 0xffff)); o1 += bf2f((u16)(y.x >> 16));
        o2 += bf2f((u16)(y.y & 0xffff)); o3 += bf2f((u16)(y.y >> 16));
    }
    if (e1 != 7) {
        uint2 y = *(const uint2*)(ybuf + 8388608 + off);
        o0 += bf2f((u16)(y.x & 0xffff)); o1 += bf2f((u16)(y.x >> 16));
        o2 += bf2f((u16)(y.y & 0xffff)); o3 += bf2f((u16)(y.y >> 16));
    }
    float4 res;
    res.x = (o0 == 0.f) ? EPS_VAL : o0;
    res.y = (o1 == 0.f) ? EPS_VAL : o1;
    res.z = (o2 == 0.f) ? EPS_VAL : o2;
    res.w = (o3 == 0.f) ? EPS_VAL : o3;
    ((float4*)out)[i] = res;
}

extern "C" void kernel_launch(void* const* d_in, const int* in_sizes, int n_in,
                              void* d_out, int out_size, void* d_ws, size_t ws_size,
                              hipStream_t stream) {
    const float* x  = (const float*)d_in[0];
    const float* wg = (const float*)d_in[1];
    const float* W1 = (const float*)d_in[2];
    const float* b1 = (const float*)d_in[3];
    const float* W2 = (const float*)d_in[4];
    const float* b2 = (const float*)d_in[5];
    (void)in_sizes; (void)n_in; (void)out_size;

    char* ws = (char*)d_ws;
    int*    cnt  = (int*)ws;                  // 7 ints @0
    int*    off  = (int*)(ws + 64);           // 8 ints @64
    float4* rec  = (float4*)(ws + 256);       // 256 KB
    uint2*  asg  = (uint2*)(ws + 262400);     // 896 KB
    u16*    xb   = (u16*)(ws + 1179904);      // 16 MB
    u16*    w1t  = (u16*)(ws + 17957120);     // 14.68 MB
    u16*    w2t  = (u16*)(ws + 32637184);     // 14.68 MB
    u16*    ybuf = (u16*)(ws + 47317248);     // 32 MB -> ends 80871680
    u16*    Hb   = (u16*)(ws + 80871680);     // 32896 rows x S bf16

    // pick largest stripe S whose H buffer fits the workspace
    int S = 128;
    const int cands[4] = {2048, 1024, 512, 256};
    for (int c = 0; c < 4; ++c) {
        if (ws_size >= 80871680ull + (size_t)32896 * cands[c] * 2) { S = cands[c]; break; }
    }
    const int passes = 2048 / S;

    hipMemsetAsync(ws, 0, 256, stream);
    k_transpose_cvt<<<dim3(64, 16, 7), 256, 0, stream>>>(W1, w1t, 512, 2048);
    k_transpose_cvt<<<dim3(16, 64, 7), 256, 0, stream>>>(W2, w2t, 2048, 512);
    k_gate<<<256, 1024, 0, stream>>>(x, wg, xb, cnt, asg, rec);
    k_prefix<<<1, 64, 0, stream>>>(cnt, off);
    for (int p = 0; p < passes; ++p) {
        int h0 = p * S;
        int NT = S / 128;
        k_e1<<<7 * MT_CAP * NT, 256, 0, stream>>>(xb, w1t, b1, cnt, off, asg, Hb, h0, S, NT);
        k_e2<<<7 * MT_CAP * 4, 256, 0, stream>>>(Hb, w2t, b2, cnt, off, asg, ybuf,
                                                 h0, S, p == 0 ? 1 : 0,
                                                 p == passes - 1 ? 1 : 0);
    }
    k_final<<<8192, 256, 0, stream>>>(x, rec, ybuf, (float*)d_out);
}